// Round 4
// baseline (225.364 us; speedup 1.0000x reference)
//
#include <hip/hip_runtime.h>
#include <hip/hip_fp16.h>

// ---------------------------------------------------------------------------
// SoftDecisionTreeEnsemble: N_TREES=15, DEPTH=3, INPUT_DIM=128, N_CLASSES=10
// R6: occupancy attack. R5's deeper intra-wave pipeline moved nothing (-1us)
// => not pipeline-depth-bound; the 2-waves/SIMD occupancy (112 resident
// weight VGPRs + 64KB LDS dbuf, both artifacts of the 8-tile block loop) is
// the remaining suspect. Now: grid=4096, ONE 64-row tile per block.
//   - LDS 32KB/block (no dbuf) -> 4 blocks/CU.
//   - weights used once/block -> loaded per-nt with a 2-deep rotate
//     (#pragma unroll 1 stops wholesale hoisting; R3 spill lesson).
//     Working set ~100 VGPR -> 4 waves/SIMD, 16 waves/CU.
//   - inter-block TLP replaces the software pipeline; single vmcnt(0)
//     before the A-gather is exactly right (all outstanding ops pre-A).
//   - wq+wbT = 32KB, L1-sized & L2-hot: per-block re-reads are ~free.
// ---------------------------------------------------------------------------

typedef float    f32x4 __attribute__((ext_vector_type(4)));
typedef _Float16 half8 __attribute__((ext_vector_type(8)));

#define TREES      15
#define IDIM       128
#define NCLS       10
#define NINT       7
#define NLVS       8
#define PER_TREE   (NINT*IDIM + NINT + NLVS*NCLS)   // 983
#define NODES      (TREES*NINT)                     // 105
#define NPAD       112                              // 7 n-tiles of 16
#define KPAD       128                              // leaf K padded
#define RSTR       272                              // s/leaf row stride bytes (136 halves)

// ---------------------------------------------------------------------------
// prep: wq[112][128] f16 (row g=7t+n, zero-padded), bq[112] f32 (zero-padded),
//       wbT[16][128] f16: wbT[c][8t+l] = softmax(leaf_logits[t][l])[c]*tw[t].
// Zero padding is load-bearing: padded nodes give z=0 -> sigmoid 0.5 ->
// garbage-free; padded leaf cols/classes contribute 0.
// ---------------------------------------------------------------------------
__global__ __launch_bounds__(256) void prep_kernel(const float* __restrict__ p,
                                                   _Float16* __restrict__ wq,
                                                   float* __restrict__ bq,
                                                   _Float16* __restrict__ wbT) {
    const int gid  = blockIdx.x * 256 + threadIdx.x;
    const int nthr = gridDim.x * 256;

    for (int i = gid; i < NPAD * IDIM; i += nthr) {
        int g = i >> 7, k = i & 127;
        float v = 0.f;
        if (g < NODES) {
            int t = g / NINT, n = g % NINT;
            v = p[t * PER_TREE + n * IDIM + k];
        }
        wq[i] = (_Float16)v;
    }
    for (int i = gid; i < NPAD; i += nthr) {
        float v = 0.f;
        if (i < NODES) {
            int t = i / NINT, n = i % NINT;
            v = p[t * PER_TREE + NINT * IDIM + n];
        }
        bq[i] = v;
    }
    const float* tl = p + TREES * PER_TREE;
    for (int i = gid; i < 16 * KPAD; i += nthr) {
        int c = i >> 7, k = i & 127;
        float v = 0.f;
        if (c < NCLS && k < TREES * NLVS) {
            int t = k >> 3, l = k & 7;
            const float* ll = p + t * PER_TREE + NINT * IDIM + NINT + l * NCLS;
            float mx = ll[0];
            #pragma unroll
            for (int j = 1; j < NCLS; ++j) mx = fmaxf(mx, ll[j]);
            float se = 0.f;
            #pragma unroll
            for (int j = 0; j < NCLS; ++j) se += __expf(ll[j] - mx);
            float lsm = __expf(ll[c] - mx) / se;

            float m2 = tl[0];
            #pragma unroll
            for (int j = 1; j < TREES; ++j) m2 = fmaxf(m2, tl[j]);
            float s2 = 0.f;
            #pragma unroll
            for (int j = 0; j < TREES; ++j) s2 += __expf(tl[j] - m2);
            float tw = __expf(tl[t] - m2) / s2;
            v = lsm * tw;
        }
        wbT[i] = (_Float16)v;
    }
}

// DMA one wave-quarter (16 rows x 512B) of an x tile into LDS, LINEAR:
// lanes 0-31 read one contiguous 512B row (perfect coalescing), lanes 32-63
// the next row. LDS dest is lane-linear -> image is row-major [16][512B].
__device__ __forceinline__ void dma_quarter(const float* __restrict__ x,
                                            long grow0, char* qdst, int lane) {
    #pragma unroll
    for (int it = 0; it < 8; ++it) {
        int r = 2 * it + (lane >> 5);
        const float* gp = x + (grow0 + r) * IDIM + (lane & 31) * 4;
        __builtin_amdgcn_global_load_lds(
            (const __attribute__((address_space(1))) void*)gp,
            (__attribute__((address_space(3))) void*)(qdst + it * 1024),
            16, 0, 0);
    }
}

// ---------------------------------------------------------------------------
__global__ __launch_bounds__(256, 4) void tree_main(const float* __restrict__ x,
                                                    const _Float16* __restrict__ wq,
                                                    const float* __restrict__ bq,
                                                    const _Float16* __restrict__ wbT,
                                                    float* __restrict__ out) {
    __shared__ __align__(16) char lds[32768];

    const int tid  = threadIdx.x;
    const int lane = tid & 63;
    const int w    = tid >> 6;        // wave id: owns rows 16w..16w+15 of tile
    const int lm   = lane & 15;
    const int lq   = lane >> 4;
    const int rg   = lane >> 2;       // Phase B row (0..15)
    const int g    = lane & 3;        // Phase B tree group

    char* qcur = &lds[w * 8192];
    const long grow = (long)blockIdx.x * 64;     // global row of this tile

    // DMA this block's tile immediately (latency hides under weight loads
    // of this block and under other resident blocks' compute).
    dma_quarter(x, grow + 16 * w, qcur, lane);

    // wbf resident (16 VGPR): Phase C class-weight fragment.
    half8 wbf[4];
    #pragma unroll
    for (int s = 0; s < 4; ++s)
        wbf[s] = *reinterpret_cast<const half8*>(wbT + lm * KPAD + 32 * s + 8 * lq);

    // preload nt=0 weight fragment (rotate buffer).
    half8 bfc[4], bfn[4];
    float bbc, bbn;
    {
        const _Float16* wp = wq + lm * IDIM;     // node = lm for nt=0
        #pragma unroll
        for (int s = 0; s < 4; ++s)
            bfc[s] = *reinterpret_cast<const half8*>(wp + 32 * s + 8 * lq);
        bbc = bq[lm];
    }

    // Everything outstanding (tile DMA + wbf + bf0) is needed before Phase A:
    // a single full drain is exactly correct here.
    asm volatile("" ::: "memory");
    __builtin_amdgcn_s_waitcnt(0x0F70);          // vmcnt(0)
    asm volatile("" ::: "memory");

    // ---- A-fragment gather from LINEAR LDS image + cvt to f16 ----
    half8 af[4];
    #pragma unroll
    for (int s = 0; s < 4; ++s) {
        int cc = 8 * s + 2 * lq;
        f32x4 f0 = *(const f32x4*)(qcur + lm * 512 + (cc       << 4));
        f32x4 f1 = *(const f32x4*)(qcur + lm * 512 + ((cc + 1) << 4));
        half8 a;
        #pragma unroll
        for (int j = 0; j < 4; ++j) {
            a[j]     = (_Float16)f0[j];
            a[j + 4] = (_Float16)f1[j];
        }
        af[s] = a;
    }

    // ---- Phase A: z-GEMM (bias in acc init) + sigmoid -> packed cols 8t+n.
    // unroll 1 + 2-deep rotate: stops the compiler from hoisting all 7 nt
    // weight fragments into registers (that's R3's 128-VGPR spill).
    #pragma unroll 1
    for (int nt = 0; nt < 7; ++nt) {
        if (nt + 1 < 7) {
            const _Float16* wp = wq + (16 * (nt + 1) + lm) * IDIM;
            #pragma unroll
            for (int s = 0; s < 4; ++s)
                bfn[s] = *reinterpret_cast<const half8*>(wp + 32 * s + 8 * lq);
            bbn = bq[16 * (nt + 1) + lm];
        }
        f32x4 acc = {bbc, bbc, bbc, bbc};
        #pragma unroll
        for (int s = 0; s < 4; ++s)
            acc = __builtin_amdgcn_mfma_f32_16x16x32_f16(af[s], bfc[s], acc, 0, 0, 0);
        int node = 16 * nt + lm;
        int col  = node + ((node * 9363) >> 16);   // node + node/7 = 8t+n
        #pragma unroll
        for (int r = 0; r < 4; ++r) {
            float z  = acc[r];                     // C/D: row=4lq+r, col=lm
            float sg = __builtin_amdgcn_rcpf(1.0f + __expf(-z));
            *(_Float16*)(qcur + (4 * lq + r) * RSTR + col * 2) = (_Float16)sg;
        }
        #pragma unroll
        for (int s = 0; s < 4; ++s) bfc[s] = bfn[s];
        bbc = bbn;
    }

    // ---- Phase B: leaf probabilities (wave-lockstep, reads before writes) --
    // b128 gather: tree t=4g+tt occupies halves [8t..8t+7] = byte 16t,
    // 16B-aligned since RSTR=272=17*16. Element 7 (col 8t+7) is never
    // written by Phase A and never used here.
    {
        const char* rowp = qcur + rg * RSTR;
        half8 hv[4];
        #pragma unroll
        for (int tt = 0; tt < 4; ++tt)
            hv[tt] = *(const half8*)(rowp + 64 * g + 16 * tt);
        half8 lv[4];
        #pragma unroll
        for (int tt = 0; tt < 4; ++tt) {
            float s0 = (float)hv[tt][0], s1 = (float)hv[tt][1], s2v = (float)hv[tt][2];
            float s3 = (float)hv[tt][3], s4 = (float)hv[tt][4], s5 = (float)hv[tt][5];
            float s6 = (float)hv[tt][6];
            float u1 = 1.f - s0, u2 = s0;
            float q1 = u1 * s1, q0 = u1 - q1;
            float q3 = u2 * s2v, q2 = u2 - q3;
            float L1 = q0 * s3, L0 = q0 - L1;
            float L3 = q1 * s4, L2 = q1 - L3;
            float L5 = q2 * s5, L4 = q2 - L5;
            float L7 = q3 * s6, L6 = q3 - L7;
            float m = (4 * g + tt < TREES) ? 1.f : 0.f;   // zero tree-15 slot
            half8 lv8;
            lv8[0] = (_Float16)(L0 * m); lv8[1] = (_Float16)(L1 * m);
            lv8[2] = (_Float16)(L2 * m); lv8[3] = (_Float16)(L3 * m);
            lv8[4] = (_Float16)(L4 * m); lv8[5] = (_Float16)(L5 * m);
            lv8[6] = (_Float16)(L6 * m); lv8[7] = (_Float16)(L7 * m);
            lv[tt] = lv8;
        }
        #pragma unroll
        for (int tt = 0; tt < 4; ++tt)
            *(half8*)(qcur + rg * RSTR + 64 * g + 16 * tt) = lv[tt];
    }

    // ---- Phase C: leaf x wbT MFMA -> out ----
    {
        half8 af2[4];
        #pragma unroll
        for (int s = 0; s < 4; ++s)
            af2[s] = *(const half8*)(qcur + lm * RSTR + 64 * s + 16 * lq);
        f32x4 a2 = {0.f, 0.f, 0.f, 0.f};
        #pragma unroll
        for (int s = 0; s < 4; ++s)
            a2 = __builtin_amdgcn_mfma_f32_16x16x32_f16(af2[s], wbf[s], a2, 0, 0, 0);
        if (lm < NCLS) {
            #pragma unroll
            for (int r = 0; r < 4; ++r)
                out[(grow + 16 * w + 4 * lq + r) * NCLS + lm] = a2[r];
        }
    }
}

// ---------------------------------------------------------------------------
extern "C" void kernel_launch(void* const* d_in, const int* in_sizes, int n_in,
                              void* d_out, int out_size, void* d_ws, size_t ws_size,
                              hipStream_t stream) {
    const float* x      = (const float*)d_in[0];
    const float* params = (const float*)d_in[1];
    float* out = (float*)d_out;

    _Float16* wq  = (_Float16*)d_ws;                             // 28672 B
    float*    bq  = (float*)((char*)d_ws + NPAD * IDIM * 2);     // 448 B
    _Float16* wbT = (_Float16*)((char*)bq + NPAD * 4);           // 4096 B

    const int batch = in_sizes[0] / IDIM;      // 262144
    const int tiles = batch / 64;              // 4096

    prep_kernel<<<8, 256, 0, stream>>>(params, wq, bq, wbT);
    tree_main<<<tiles, 256, 0, stream>>>(x, wq, bq, wbT, out);
}